// Round 1
// baseline (1147.506 us; speedup 1.0000x reference)
//
#include <hip/hip_runtime.h>
#include <hip/hip_cooperative_groups.h>
#include <cstddef>

namespace cg = cooperative_groups;

#define NN 256
#define DD 1024
#define CC 4
#define NEGF (-1e30f)
#define RSPLIT 4
#define GRID_BLOCKS 512

// Static device scratch (rewritten every launch; no cross-launch state relied on)
__device__ float g_zp[RSPLIT][NN][DD];   // row-partial sums of z per node
__device__ int g_cidx[NN][CC];           // compacted child indices
__device__ int g_cdep[NN][CC];           // compacted dep labels
__device__ int g_nch[NN];                // effective child count
__device__ int g_lvl[NN];                // dependency level (leaf = 0)
__device__ unsigned char g_reach[NN];    // reachable from root
__device__ int g_order[NN];              // internal reachable nodes, bucketed by level
__device__ int g_lstart[NN + 2];         // level -> offset into g_order
__device__ int g_nlev;                   // max level

__device__ inline float child_z(const float* __restrict__ emb, int ch, int j) {
  if (g_nch[ch] == 0) return emb[ch * DD + j];  // leaf: z = x
  return g_zp[0][ch][j] + g_zp[1][ch][j] + g_zp[2][ch][j] + g_zp[3][ch][j];
}

__global__ void dep_enc_kernel(const float* __restrict__ emb,
                               const float* __restrict__ par,
                               const int* __restrict__ cidx,
                               const int* __restrict__ cdep,
                               const unsigned char* __restrict__ cmask,
                               float* __restrict__ out) {
  cg::grid_group grid = cg::this_grid();
  __shared__ float xs[256];

  // ---------- Phase 1: build schedule (single thread; trivial work) ----------
  if (blockIdx.x == 0 && threadIdx.x == 0) {
    // Detect bool storage: u8 (1 byte/elem) vs int32 (4 bytes/elem).
    // Root mask (elements 1020..1023) is guaranteed all-True by setup.
    // u8 storage  -> bytes 1021..1023 are mask[255][1..3] == 1.
    // i32 storage -> bytes 1021..1023 are high bytes of element 255 == 0.
    bool m_u8 = (cmask[1021] == 1 && cmask[1022] == 1 && cmask[1023] == 1);
    const int* m32 = (const int*)cmask;
    for (int i = 0; i < NN; ++i) {
      int nc = 0, lv = 0;
      for (int c = 0; c < CC; ++c) {
        bool mk = m_u8 ? (cmask[i * CC + c] != 0) : (m32[i * CC + c] != 0);
        if (mk) {
          int ch = cidx[i * CC + c];
          g_cidx[i][nc] = ch;
          g_cdep[i][nc] = cdep[i * CC + c];
          int cl = g_lvl[ch] + 1;  // ch < i, already computed
          if (cl > lv) lv = cl;
          ++nc;
        }
      }
      g_nch[i] = nc;
      g_lvl[i] = nc ? lv : 0;
      g_reach[i] = 0;
    }
    // Reachability from root: children have smaller index -> one descending pass
    g_reach[NN - 1] = 1;
    for (int i = NN - 1; i >= 1; --i) {
      if (g_reach[i]) {
        for (int c = 0; c < g_nch[i]; ++c) g_reach[g_cidx[i][c]] = 1;
      }
    }
    int maxl = 0;
    for (int i = 0; i < NN; ++i)
      if (g_reach[i] && g_nch[i] > 0 && g_lvl[i] > maxl) maxl = g_lvl[i];
    int cnt[NN + 1];
    for (int L = 0; L <= maxl; ++L) cnt[L] = 0;
    for (int i = 0; i < NN; ++i)
      if (g_reach[i] && g_nch[i] > 0) cnt[g_lvl[i]]++;
    g_lstart[1] = 0;
    for (int L = 1; L <= maxl; ++L) g_lstart[L + 1] = g_lstart[L] + cnt[L];
    int cur[NN + 1];
    for (int L = 1; L <= maxl; ++L) cur[L] = g_lstart[L];
    for (int i = 0; i < NN; ++i)
      if (g_reach[i] && g_nch[i] > 0) g_order[cur[g_lvl[i]]++] = i;
    g_nlev = maxl;
  }
  grid.sync();

  // ---------- Phase 2: level-by-level compute ----------
  const int nlev = g_nlev;
  for (int L = 1; L <= nlev; ++L) {
    const int s = g_lstart[L];
    const int nunits = (g_lstart[L + 1] - s) << 4;  // 4 rblk x 4 cblk per node
    for (int u = blockIdx.x; u < nunits; u += gridDim.x) {
      const int node = g_order[s + (u >> 4)];
      const int rblk = (u >> 2) & 3;
      const int cblk = u & 3;
      const int j = (cblk << 8) | threadIdx.x;
      const int nc = g_nch[node];

      const float* Pp[4];
      float uu[4];
#pragma unroll
      for (int c = 0; c < 4; ++c) {
        const int cc = (c < nc) ? c : 0;  // duplicate child 0: max unchanged
        const int ch = g_cidx[node][cc];
        Pp[c] = par + (size_t)g_cdep[node][cc] * (DD * DD);
        uu[c] = fmaxf(child_z(emb, ch, j), 0.0f);
      }

      __syncthreads();  // protect xs from previous unit
      xs[threadIdx.x] = emb[node * DD + (rblk << 8) + threadIdx.x];
      __syncthreads();

      const float* p0 = Pp[0] + (size_t)(rblk << 8) * DD + j;
      const float* p1 = Pp[1] + (size_t)(rblk << 8) * DD + j;
      const float* p2 = Pp[2] + (size_t)(rblk << 8) * DD + j;
      const float* p3 = Pp[3] + (size_t)(rblk << 8) * DD + j;
      float acc = 0.0f;
#pragma unroll 4
      for (int r0 = 0; r0 < 256; ++r0) {
        float m = fmaxf(p0[(size_t)r0 * DD] * uu[0], p1[(size_t)r0 * DD] * uu[1]);
        m = fmaxf(m, p2[(size_t)r0 * DD] * uu[2]);
        m = fmaxf(m, p3[(size_t)r0 * DD] * uu[3]);
        acc = fmaf(xs[r0], m, acc);
      }
      g_zp[rblk][node][j] = acc;
    }
    grid.sync();
  }

  // ---------- Output: root z ----------
  const int gtid = blockIdx.x * blockDim.x + threadIdx.x;
  const int gstride = gridDim.x * blockDim.x;
  for (int j = gtid; j < DD; j += gstride) {
    float v;
    if (g_nch[NN - 1] == 0) {
      v = emb[(NN - 1) * DD + j];
    } else {
      v = g_zp[0][NN - 1][j] + g_zp[1][NN - 1][j] + g_zp[2][NN - 1][j] +
          g_zp[3][NN - 1][j];
    }
    out[j] = v;
  }
}

extern "C" void kernel_launch(void* const* d_in, const int* in_sizes, int n_in,
                              void* d_out, int out_size, void* d_ws, size_t ws_size,
                              hipStream_t stream) {
  const float* emb = (const float*)d_in[0];
  const float* par = (const float*)d_in[1];
  const int* cidx = (const int*)d_in[2];
  const int* cdep = (const int*)d_in[3];
  const unsigned char* cmask = (const unsigned char*)d_in[4];
  float* out = (float*)d_out;

  void* args[] = {(void*)&emb, (void*)&par, (void*)&cidx,
                  (void*)&cdep, (void*)&cmask, (void*)&out};
  hipLaunchCooperativeKernel((void*)dep_enc_kernel, dim3(GRID_BLOCKS),
                             dim3(256), args, 0, stream);
}

// Round 3
// 865.279 us; speedup vs baseline: 1.3262x; 1.3262x over previous
//
#include <hip/hip_runtime.h>
#include <hip/hip_cooperative_groups.h>
#include <cstddef>

namespace cg = cooperative_groups;

#define NN 256
#define DD 1024
#define CC 4
#define RS 16              // row-split partials per node
#define ROWS (DD / RS)     // 64 rows per unit
#define NB 512             // grid blocks (proven cooperative-launch capacity)

// Static device scratch — fully rewritten before use on every launch.
__device__ float g_zp[RS][NN][DD];   // row-partial sums of z per node
__device__ int g_cidx[NN][CC];       // compacted (duplicated) child indices
__device__ int g_cdep[NN][CC];       // compacted (duplicated) dep labels
__device__ int g_nch[NN];            // effective child count
__device__ int g_order[NN];          // internal reachable nodes bucketed by level
__device__ int g_lstart[NN + 2];     // level -> offset into g_order
__device__ int g_nlev;

__global__ void dep_enc_kernel(const float* __restrict__ emb,
                               const float* __restrict__ par,
                               const int* __restrict__ cidx,
                               const int* __restrict__ cdep,
                               const unsigned char* __restrict__ cmask,
                               float* __restrict__ out) {
  cg::grid_group grid = cg::this_grid();

  __shared__ int s_ci[NN][CC];
  __shared__ int s_cd[NN][CC];
  __shared__ int s_lvl[NN];
  __shared__ unsigned char s_reach[NN];
  __shared__ int s_cnt[NN];
  __shared__ int s_pos[NN];
  __shared__ int s_flag;
  __shared__ float xs[ROWS];

  const int tid = threadIdx.x;

  // ---------------- Phase 1: schedule build (block 0, parallel) ----------------
  if (blockIdx.x == 0) {
    const int i = tid;  // one node per thread
    // Detect mask storage: u8 vs int32. Root mask (last 4 elements) all-True.
    if (i == 0) s_flag = (cmask[1021] == 1 && cmask[1022] == 1 && cmask[1023] == 1);
    __syncthreads();
    const bool m_u8 = (s_flag != 0);
    const int* m32 = (const int*)cmask;

    int ci[CC], cd[CC];
    int nc = 0;
#pragma unroll
    for (int c = 0; c < CC; ++c) {
      bool mk = m_u8 ? (cmask[i * CC + c] != 0) : (m32[i * CC + c] != 0);
      if (mk) {
        ci[nc] = cidx[i * CC + c];
        cd[nc] = cdep[i * CC + c];
        ++nc;
      }
    }
    if (nc == 0) {
      for (int c = 0; c < CC; ++c) { ci[c] = 0; cd[c] = 0; }
    } else {
      for (int c = nc; c < CC; ++c) { ci[c] = ci[0]; cd[c] = cd[0]; }  // dup: max unchanged
    }
#pragma unroll
    for (int c = 0; c < CC; ++c) { s_ci[i][c] = ci[c]; s_cd[i][c] = cd[c]; }
    s_lvl[i] = 0;
    s_reach[i] = (i == NN - 1) ? 1 : 0;
    __syncthreads();

    // Level fixpoint (monotone relaxation; converges in <= depth passes)
    for (int it = 0; it < NN + 2; ++it) {
      if (tid == 0) s_flag = 0;
      __syncthreads();
      if (nc) {
        int lv = 0;
#pragma unroll
        for (int c = 0; c < CC; ++c) lv = max(lv, s_lvl[ci[c]]);
        lv += 1;
        if (lv != s_lvl[i]) { s_lvl[i] = lv; s_flag = 1; }
      }
      __syncthreads();
      int ch = s_flag;
      __syncthreads();
      if (!ch) break;
    }

    // Reachability fixpoint (root downward)
    for (int it = 0; it < NN + 2; ++it) {
      if (tid == 0) s_flag = 0;
      __syncthreads();
      if (s_reach[i] && nc) {
#pragma unroll
        for (int c = 0; c < CC; ++c)
          if (!s_reach[ci[c]]) { s_reach[ci[c]] = 1; s_flag = 1; }
      }
      __syncthreads();
      int ch = s_flag;
      __syncthreads();
      if (!ch) break;
    }

    // Bucket internal reachable nodes by level
    s_cnt[i] = 0;
    __syncthreads();
    const bool active = (s_reach[i] != 0) && (nc > 0);
    const int lv = s_lvl[i];
    if (active) atomicAdd(&s_cnt[lv], 1);
    __syncthreads();
    if (tid == 0) {
      int maxl = 0;
      for (int L = 1; L < NN; ++L)
        if (s_cnt[L]) maxl = L;
      int off = 0;
      for (int L = 1; L <= maxl; ++L) {
        s_pos[L] = off;
        g_lstart[L] = off;
        off += s_cnt[L];
      }
      g_lstart[maxl + 1] = off;
      g_nlev = maxl;
    }
    __syncthreads();
    if (active) {
      int pos = atomicAdd(&s_pos[lv], 1);
      g_order[pos] = i;
    }
    g_nch[i] = nc;
#pragma unroll
    for (int c = 0; c < CC; ++c) { g_cidx[i][c] = ci[c]; g_cdep[i][c] = cd[c]; }
  }
  grid.sync();

  // ---------------- Phase 2: level-by-level compute ----------------
  const int nlev = g_nlev;
  const int j0 = tid << 2;  // 4 consecutive columns per thread (float4)
  for (int L = 1; L <= nlev; ++L) {
    const int s = g_lstart[L];
    const int nunits = (g_lstart[L + 1] - s) << 4;  // RS units per node
    for (int u = blockIdx.x; u < nunits; u += gridDim.x) {
      const int node = g_order[s + (u >> 4)];
      const int rblk = u & (RS - 1);

      // Gather relu(z_child) for 4 (duplicated) children, 4 cols each
      float4 uu[CC];
      const float* pp[CC];
#pragma unroll
      for (int c = 0; c < CC; ++c) {
        const int ch = g_cidx[node][c];
        pp[c] = par + (size_t)g_cdep[node][c] * (DD * DD);
        float4 sz;
        if (g_nch[ch] == 0) {
          sz = *(const float4*)(emb + (size_t)ch * DD + j0);
        } else {
          sz = *(const float4*)(&g_zp[0][ch][j0]);
#pragma unroll
          for (int p = 1; p < RS; ++p) {
            float4 t = *(const float4*)(&g_zp[p][ch][j0]);
            sz.x += t.x; sz.y += t.y; sz.z += t.z; sz.w += t.w;
          }
        }
        uu[c].x = fmaxf(sz.x, 0.f); uu[c].y = fmaxf(sz.y, 0.f);
        uu[c].z = fmaxf(sz.z, 0.f); uu[c].w = fmaxf(sz.w, 0.f);
      }

      __syncthreads();  // protect xs from previous unit
      if (tid < ROWS) xs[tid] = emb[(size_t)node * DD + (rblk * ROWS) + tid];
      __syncthreads();

      const size_t rb = (size_t)(rblk * ROWS) * DD + j0;
      const float* p0 = pp[0] + rb;
      const float* p1 = pp[1] + rb;
      const float* p2 = pp[2] + rb;
      const float* p3 = pp[3] + rb;
      float4 acc = {0.f, 0.f, 0.f, 0.f};
#pragma unroll 8
      for (int r = 0; r < ROWS; ++r) {
        const float4 a = *(const float4*)(p0 + (size_t)r * DD);
        const float4 b = *(const float4*)(p1 + (size_t)r * DD);
        const float4 c = *(const float4*)(p2 + (size_t)r * DD);
        const float4 d = *(const float4*)(p3 + (size_t)r * DD);
        float4 m;
        m.x = fmaxf(fmaxf(a.x * uu[0].x, b.x * uu[1].x), fmaxf(c.x * uu[2].x, d.x * uu[3].x));
        m.y = fmaxf(fmaxf(a.y * uu[0].y, b.y * uu[1].y), fmaxf(c.y * uu[2].y, d.y * uu[3].y));
        m.z = fmaxf(fmaxf(a.z * uu[0].z, b.z * uu[1].z), fmaxf(c.z * uu[2].z, d.z * uu[3].z));
        m.w = fmaxf(fmaxf(a.w * uu[0].w, b.w * uu[1].w), fmaxf(c.w * uu[2].w, d.w * uu[3].w));
        const float xr = xs[r];
        acc.x = fmaf(xr, m.x, acc.x);
        acc.y = fmaf(xr, m.y, acc.y);
        acc.z = fmaf(xr, m.z, acc.z);
        acc.w = fmaf(xr, m.w, acc.w);
      }
      *(float4*)(&g_zp[rblk][node][j0]) = acc;
    }
    grid.sync();
  }

  // ---------------- Output: root z ----------------
  const int gtid = blockIdx.x * blockDim.x + tid;
  if (gtid < (DD >> 2)) {
    const int jo = gtid << 2;
    float4 v;
    if (g_nch[NN - 1] == 0) {
      v = *(const float4*)(emb + (size_t)(NN - 1) * DD + jo);
    } else {
      v = *(const float4*)(&g_zp[0][NN - 1][jo]);
#pragma unroll
      for (int p = 1; p < RS; ++p) {
        float4 t = *(const float4*)(&g_zp[p][NN - 1][jo]);
        v.x += t.x; v.y += t.y; v.z += t.z; v.w += t.w;
      }
    }
    *(float4*)((float*)out + jo) = v;
  }
}

extern "C" void kernel_launch(void* const* d_in, const int* in_sizes, int n_in,
                              void* d_out, int out_size, void* d_ws, size_t ws_size,
                              hipStream_t stream) {
  const float* emb = (const float*)d_in[0];
  const float* par = (const float*)d_in[1];
  const int* cidx = (const int*)d_in[2];
  const int* cdep = (const int*)d_in[3];
  const unsigned char* cmask = (const unsigned char*)d_in[4];
  float* out = (float*)d_out;

  void* args[] = {(void*)&emb, (void*)&par, (void*)&cidx,
                  (void*)&cdep, (void*)&cmask, (void*)&out};
  hipLaunchCooperativeKernel((void*)dep_enc_kernel, dim3(NB), dim3(256), args, 0,
                             stream);
}